// Round 1
// baseline (1398.056 us; speedup 1.0000x reference)
//
#include <hip/hip_runtime.h>

#define EPS 1e-6f

constexpr int C    = 128;      // channels
constexpr int HW   = 65536;    // 256*256 pixels per batch image
constexpr int TILE = 64;       // pixels per block
constexpr int NT   = 256;      // threads per block

__global__ __launch_bounds__(NT, 4) void spnorm_kernel(
    const float* __restrict__ x, const float* __restrict__ W,
    const float* __restrict__ bias, float* __restrict__ out)
{
    __shared__ float xs[C][TILE];      // 32 KB: x tile, later normalized in place
    __shared__ float red1[4][TILE];
    __shared__ float red2[4][TILE];
    __shared__ float u_s[TILE], seps_s[TILE], inv_s[TILE];

    const int tid  = threadIdx.x;
    const int lane = tid & 63;
    const int wv   = tid >> 6;
    const int pix0  = blockIdx.x * TILE;      // global pixel index of tile start
    const int batch = pix0 >> 16;             // / 65536
    const int hw0   = pix0 & 65535;
    const int base  = batch * (C * HW) + hw0; // element offset of (batch, c=0, hw0)

    // ---- stage x tile into LDS, float4 coalesced ----
    // 128*64 = 8192 floats = 2048 float4; 256 threads x 8 iters
    float* xsf = &xs[0][0];
    #pragma unroll
    for (int it = 0; it < 8; ++it) {
        int i4 = it * NT + tid;        // 0..2047
        int c  = i4 >> 4;              // 16 float4 per row of 64
        int p4 = i4 & 15;
        float4 v = *reinterpret_cast<const float4*>(x + base + c * HW + p4 * 4);
        *reinterpret_cast<float4*>(&xs[c][p4 * 4]) = v;
    }
    __syncthreads();

    // ---- per-pixel mean / unbiased var (one-pass), cooperative ----
    {
        const int p  = lane;
        const int c0 = wv * 32;
        float s1 = 0.f, s2 = 0.f;
        #pragma unroll
        for (int i = 0; i < 32; ++i) {
            float v = xs[c0 + i][p];
            s1 += v;
            s2 += v * v;
        }
        red1[wv][p] = s1;
        red2[wv][p] = s2;
    }
    __syncthreads();
    if (tid < TILE) {
        const int p = tid;
        float s1 = red1[0][p] + red1[1][p] + red1[2][p] + red1[3][p];
        float s2 = red2[0][p] + red2[1][p] + red2[2][p] + red2[3][p];
        float u   = s1 * (1.0f / 128.0f);
        float var = (s2 - s1 * u) * (1.0f / 127.0f);   // ddof=1
        var = fmaxf(var, 0.0f);
        float seps = sqrtf(var) + EPS;
        u_s[p]    = u;
        seps_s[p] = seps;
        inv_s[p]  = 1.0f / seps;
    }
    __syncthreads();

    // ---- normalize in place ----
    {
        const float u  = u_s[lane];     // i & 63 == lane for all iters
        const float iv = inv_s[lane];
        #pragma unroll
        for (int it = 0; it < 32; ++it) {
            int i = it * NT + tid;      // 0..8191, i%64 == lane
            xsf[i] = (xsf[i] - u) * iv;
        }
    }
    __syncthreads();

    // ---- 1x1 conv (matvec vs W rows) + recover x + multiply + store ----
    {
        const int p      = lane;
        const int o_base = __builtin_amdgcn_readfirstlane(wv * 32); // force SGPR -> s_load of W
        const float u    = u_s[p];
        const float seps = seps_s[p];

        for (int og = 0; og < 32; og += 4) {
            const int o = o_base + og;
            const float* w0 = W + o * C;           // uniform -> scalar loads
            float a0 = bias[o];
            float a1 = bias[o + 1];
            float a2 = bias[o + 2];
            float a3 = bias[o + 3];
            #pragma unroll
            for (int c = 0; c < C; ++c) {
                float nv = xs[c][p];
                a0 = fmaf(nv, w0[c],          a0);
                a1 = fmaf(nv, w0[C + c],      a1);
                a2 = fmaf(nv, w0[2 * C + c],  a2);
                a3 = fmaf(nv, w0[3 * C + c],  a3);
            }
            // original x_o = n_o * (s+eps) + u  (xs holds normalized values)
            float x0 = fmaf(xs[o][p],     seps, u);
            float x1 = fmaf(xs[o + 1][p], seps, u);
            float x2 = fmaf(xs[o + 2][p], seps, u);
            float x3 = fmaf(xs[o + 3][p], seps, u);
            out[base + (o)     * HW + p] = x0 * a0;
            out[base + (o + 1) * HW + p] = x1 * a1;
            out[base + (o + 2) * HW + p] = x2 * a2;
            out[base + (o + 3) * HW + p] = x3 * a3;
        }
    }
}

extern "C" void kernel_launch(void* const* d_in, const int* in_sizes, int n_in,
                              void* d_out, int out_size, void* d_ws, size_t ws_size,
                              hipStream_t stream) {
    const float* x = (const float*)d_in[0];
    const float* W = (const float*)d_in[1];
    const float* b = (const float*)d_in[2];
    float* out     = (float*)d_out;

    const int npix = 8 * HW;               // 524288 pixels
    dim3 grid(npix / TILE);                // 8192 blocks
    spnorm_kernel<<<grid, NT, 0, stream>>>(x, W, b, out);
}

// Round 3
// 217.534 us; speedup vs baseline: 6.4268x; 6.4268x over previous
//
#include <hip/hip_runtime.h>
#include <hip/hip_bf16.h>

#define EPS 1e-6f

constexpr int C    = 128;
constexpr int HW   = 65536;    // 256*256
constexpr int TILE = 256;      // pixels per block
constexpr int NT   = 512;      // threads per block (8 waves)

struct __align__(8) bh4 { __hip_bfloat16 a, b, c, d; };

__global__ __launch_bounds__(NT, 4) void spnorm_kernel(
    const float* __restrict__ x, const float* __restrict__ W,
    const float* __restrict__ bias, float* __restrict__ out)
{
    __shared__ __hip_bfloat16 nb[C][TILE];                 // 64 KB: x tile (bf16), normalized in place
    __shared__ float red1[4][TILE];                        // 4 KB
    __shared__ float red2[4][TILE];                        // 4 KB
    __shared__ __align__(16) float u_s[TILE];
    __shared__ __align__(16) float iv_s[TILE];
    __shared__ __align__(16) float se_s[TILE];

    const int tid  = threadIdx.x;
    const int lane = tid & 63;
    const int wv   = tid >> 6;
    const int batch = blockIdx.x >> 8;                     // 256 blocks per batch image
    const int hw0   = (blockIdx.x & 255) * TILE;
    const int base  = batch * (C * HW) + hw0;

    // ---- Phase 1: stage x (fp32 -> bf16), 1 KB contiguous per channel row ----
    #pragma unroll
    for (int it = 0; it < 16; ++it) {
        int i4 = it * NT + tid;            // 0..8191 float4 chunks
        int c  = i4 >> 6;                  // 64 float4 per 256-px row
        int p4 = (i4 & 63) << 2;
        float4 v = *reinterpret_cast<const float4*>(x + base + c * HW + p4);
        bh4 h;
        h.a = __float2bfloat16(v.x);
        h.b = __float2bfloat16(v.y);
        h.c = __float2bfloat16(v.z);
        h.d = __float2bfloat16(v.w);
        *reinterpret_cast<bh4*>(&nb[c][p4]) = h;
    }
    __syncthreads();

    // ---- Phase 2: per-pixel mean / unbiased var partial sums ----
    {
        int g  = tid >> 7;                 // 4 channel-groups of 32
        int p0 = (tid & 127) * 2;          // pixel pair
        float s1a = 0.f, s1b = 0.f, s2a = 0.f, s2b = 0.f;
        #pragma unroll
        for (int i = 0; i < 32; ++i) {
            int c = g * 32 + i;
            float a = __bfloat162float(nb[c][p0]);
            float b = __bfloat162float(nb[c][p0 + 1]);
            s1a += a; s2a = fmaf(a, a, s2a);
            s1b += b; s2b = fmaf(b, b, s2b);
        }
        red1[g][p0] = s1a; red1[g][p0 + 1] = s1b;
        red2[g][p0] = s2a; red2[g][p0 + 1] = s2b;
    }
    __syncthreads();
    if (tid < TILE) {
        float s1 = red1[0][tid] + red1[1][tid] + red1[2][tid] + red1[3][tid];
        float s2 = red2[0][tid] + red2[1][tid] + red2[2][tid] + red2[3][tid];
        float u   = s1 * (1.0f / 128.0f);
        float var = fmaxf((s2 - s1 * u) * (1.0f / 127.0f), 0.0f);
        float se  = sqrtf(var) + EPS;
        u_s[tid]  = u;
        se_s[tid] = se;
        iv_s[tid] = 1.0f / se;
    }
    __syncthreads();

    // ---- Phase 3: normalize in place (bf16) ----
    #pragma unroll
    for (int it = 0; it < 16; ++it) {
        int i4 = it * NT + tid;
        int c  = i4 >> 6;
        int p4 = (i4 & 63) << 2;
        bh4 h = *reinterpret_cast<bh4*>(&nb[c][p4]);
        float4 uu = *reinterpret_cast<float4*>(&u_s[p4]);
        float4 vv = *reinterpret_cast<float4*>(&iv_s[p4]);
        h.a = __float2bfloat16((__bfloat162float(h.a) - uu.x) * vv.x);
        h.b = __float2bfloat16((__bfloat162float(h.b) - uu.y) * vv.y);
        h.c = __float2bfloat16((__bfloat162float(h.c) - uu.z) * vv.z);
        h.d = __float2bfloat16((__bfloat162float(h.d) - uu.w) * vv.w);
        *reinterpret_cast<bh4*>(&nb[c][p4]) = h;
    }
    __syncthreads();

    // ---- Phase 4: conv. wave wv owns 16 output channels; lane owns 4 consecutive px.
    //      W read fp32 directly via wave-uniform scalar loads (no workspace, no 2nd kernel).
    {
        const int obase = __builtin_amdgcn_readfirstlane(wv << 4);
        const int p     = lane << 2;

        float4 acc[16];
        #pragma unroll
        for (int i = 0; i < 16; ++i) {
            float b = bias[obase + i];
            acc[i] = make_float4(b, b, b, b);
        }

        for (int c4 = 0; c4 < C / 4; ++c4) {     // 32 chunks of 4 channels
            #pragma unroll
            for (int j = 0; j < 4; ++j) {
                const int c = c4 * 4 + j;
                bh4 h = *reinterpret_cast<const bh4*>(&nb[c][p]);
                float4 n4;
                n4.x = __bfloat162float(h.a);
                n4.y = __bfloat162float(h.b);
                n4.z = __bfloat162float(h.c);
                n4.w = __bfloat162float(h.d);
                #pragma unroll
                for (int i = 0; i < 16; ++i) {
                    float w = W[(obase + i) * C + c];   // uniform addr -> s_load
                    float4& a = acc[i];
                    a.x = fmaf(n4.x, w, a.x);
                    a.y = fmaf(n4.y, w, a.y);
                    a.z = fmaf(n4.z, w, a.z);
                    a.w = fmaf(n4.w, w, a.w);
                }
            }
        }

        // ---- Phase 5: recover x = n*(s+eps)+u, multiply, store 1 KB-contiguous float4 ----
        float4 uu = *reinterpret_cast<float4*>(&u_s[p]);
        float4 se = *reinterpret_cast<float4*>(&se_s[p]);
        #pragma unroll
        for (int i = 0; i < 16; ++i) {
            bh4 h = *reinterpret_cast<bh4*>(&nb[obase + i][p]);
            float4 a = acc[i];
            float4 o4;
            o4.x = fmaf(__bfloat162float(h.a), se.x, uu.x) * a.x;
            o4.y = fmaf(__bfloat162float(h.b), se.y, uu.y) * a.y;
            o4.z = fmaf(__bfloat162float(h.c), se.z, uu.z) * a.z;
            o4.w = fmaf(__bfloat162float(h.d), se.w, uu.w) * a.w;
            *reinterpret_cast<float4*>(out + base + (obase + i) * HW + p) = o4;
        }
    }
}

extern "C" void kernel_launch(void* const* d_in, const int* in_sizes, int n_in,
                              void* d_out, int out_size, void* d_ws, size_t ws_size,
                              hipStream_t stream) {
    const float* x = (const float*)d_in[0];
    const float* W = (const float*)d_in[1];
    const float* b = (const float*)d_in[2];
    float* out     = (float*)d_out;

    const int nblk = 8 * HW / TILE;                 // 2048 blocks
    spnorm_kernel<<<nblk, NT, 0, stream>>>(x, W, b, out);
}

// Round 4
// 123.385 us; speedup vs baseline: 11.3308x; 1.7631x over previous
//
#include <hip/hip_runtime.h>

#define EPS 1e-6f

constexpr int C    = 128;
constexpr int HW   = 65536;    // 256*256
constexpr int TILE = 128;      // pixels per block
constexpr int NT   = 512;      // 8 waves

typedef __attribute__((ext_vector_type(8))) short bf16x8;
typedef __attribute__((ext_vector_type(4))) float f32x4;

__device__ __forceinline__ unsigned short f2bf(float f) {   // RNE
    unsigned u = __float_as_uint(f);
    u += 0x7fff + ((u >> 16) & 1);
    return (unsigned short)(u >> 16);
}
__device__ __forceinline__ float bf2f(unsigned short u) {
    return __uint_as_float(((unsigned)u) << 16);
}
__device__ __forceinline__ unsigned pack2(float lo, float hi) {
    return (unsigned)f2bf(lo) | ((unsigned)f2bf(hi) << 16);
}

__global__ __launch_bounds__(NT, 4) void spnorm_kernel(
    const float* __restrict__ x, const float* __restrict__ W,
    const float* __restrict__ bias, float* __restrict__ out)
{
    // One 32 KB buffer, two lives:
    //   phases 1-2: nb[c][p]   raw bf16 x tile (plain layout)
    //   phases 3+ : nbT[p][c]  normalized, transposed, XOR-swizzled (byte ^= (p&15)<<4)
    // Safe overlay: nb's last read is before the red-barrier; nbT's first write is
    // after the finalize barrier.
    __shared__ unsigned short buf[TILE * C];               // 32 KB
    __shared__ float red1[4][TILE], red2[4][TILE];         // 2 KB
    __shared__ float u_s[TILE], iv_s[TILE], se_s[TILE];    // 1.5 KB

    const int tid  = threadIdx.x;
    const int l    = tid & 63;
    const int wv   = tid >> 6;
    const int batch = blockIdx.x >> 9;                     // 512 blocks per image
    const int hw0   = (blockIdx.x & 511) * TILE;
    const int base  = batch * (C * HW) + hw0;

    // ---- A-fragments: W (fp32 -> bf16) straight from global, issued early ----
    // A[m=o][k=c]: lane holds row o = wv*16 + (l&15), k-octet (l>>4)*8 + j.
    const int arow  = (wv << 4) + (l & 15);
    const int acol0 = (l >> 4) << 3;
    bf16x8 afrag[4];
    #pragma unroll
    for (int kk = 0; kk < 4; ++kk) {
        const float* wp = W + arow * C + kk * 32 + acol0;
        float4 wa = *reinterpret_cast<const float4*>(wp);
        float4 wb = *reinterpret_cast<const float4*>(wp + 4);
        bf16x8 f;
        f[0] = (short)f2bf(wa.x); f[1] = (short)f2bf(wa.y);
        f[2] = (short)f2bf(wa.z); f[3] = (short)f2bf(wa.w);
        f[4] = (short)f2bf(wb.x); f[5] = (short)f2bf(wb.y);
        f[6] = (short)f2bf(wb.z); f[7] = (short)f2bf(wb.w);
        afrag[kk] = f;
    }
    // D rows (l>>4)*4+r  ->  output channels od..od+3
    const int od = (wv << 4) + ((l >> 4) << 2);
    const f32x4 binit = { bias[od], bias[od + 1], bias[od + 2], bias[od + 3] };

    // ---- Phase 1: stage x (fp32 -> bf16) into nb[c][p], coalesced float4 ----
    {
        unsigned short* nb = buf;
        #pragma unroll
        for (int it = 0; it < 8; ++it) {
            int i4 = it * NT + tid;            // 4096 float4 chunks
            int c  = i4 >> 5;                  // 32 float4 per 128-px row
            int p4 = (i4 & 31) << 2;
            float4 v = *reinterpret_cast<const float4*>(x + base + c * HW + p4);
            uint2 d;
            d.x = pack2(v.x, v.y);
            d.y = pack2(v.z, v.w);
            *reinterpret_cast<uint2*>(&nb[c * TILE + p4]) = d;
        }
    }
    __syncthreads();

    // ---- Phase 2: stats; thread (p, q) reads c = q*32..q*32+31, caches in regs ----
    const int p = tid & 127;
    const int q = tid >> 7;
    float v[32];
    {
        const unsigned short* nb = buf;
        float s1 = 0.f, s2 = 0.f;
        #pragma unroll
        for (int i = 0; i < 32; ++i) {
            float t = bf2f(nb[(q * 32 + i) * TILE + p]);
            v[i] = t;
            s1 += t;
            s2 = fmaf(t, t, s2);
        }
        red1[q][p] = s1;
        red2[q][p] = s2;
    }
    __syncthreads();
    if (tid < TILE) {
        float s1 = red1[0][tid] + red1[1][tid] + red1[2][tid] + red1[3][tid];
        float s2 = red2[0][tid] + red2[1][tid] + red2[2][tid] + red2[3][tid];
        float u   = s1 * (1.0f / 128.0f);
        float var = fmaxf((s2 - s1 * u) * (1.0f / 127.0f), 0.0f);
        float se  = sqrtf(var) + EPS;
        u_s[tid]  = u;
        se_s[tid] = se;
        iv_s[tid] = 1.0f / se;
    }
    __syncthreads();

    // ---- Phase 3: normalize regs, pack, write transposed+swizzled nbT[p][c] ----
    {
        char* nbTc = (char*)buf;
        const float u  = u_s[p];
        const float iv = iv_s[p];
        const int rowoff = p * 256;            // 128 ushort per row
        const int swz    = (p & 15) << 4;
        #pragma unroll
        for (int o8 = 0; o8 < 4; ++o8) {
            float n0 = (v[o8 * 8 + 0] - u) * iv;
            float n1 = (v[o8 * 8 + 1] - u) * iv;
            float n2 = (v[o8 * 8 + 2] - u) * iv;
            float n3 = (v[o8 * 8 + 3] - u) * iv;
            float n4 = (v[o8 * 8 + 4] - u) * iv;
            float n5 = (v[o8 * 8 + 5] - u) * iv;
            float n6 = (v[o8 * 8 + 6] - u) * iv;
            float n7 = (v[o8 * 8 + 7] - u) * iv;
            uint4 d;
            d.x = pack2(n0, n1);
            d.y = pack2(n2, n3);
            d.z = pack2(n4, n5);
            d.w = pack2(n6, n7);
            int byte = (rowoff + (q * 4 + o8) * 16) ^ swz;   // c-octet q*4+o8
            *reinterpret_cast<uint4*>(nbTc + byte) = d;
        }
    }
    __syncthreads();

    // ---- Phase 4: MFMA conv + epilogue. Wave wv: 16 o x 128 px (8 tiles x 4 K-steps) ----
    {
        const char* nbTc = (const char*)buf;
        const int pcol = l & 15;
        const int koff = (l >> 4) << 4;        // k-octet byte offset within 64 B K-step
        const int swz  = pcol << 4;
        float* outp = out + base;
        #pragma unroll
        for (int pt = 0; pt < 8; ++pt) {
            const int pp     = (pt << 4) + pcol;
            const int rowoff = pp * 256;
            f32x4 acc = binit;
            #pragma unroll
            for (int kk = 0; kk < 4; ++kk) {
                int byte = (rowoff + kk * 64 + koff) ^ swz;
                bf16x8 bfrag = *reinterpret_cast<const bf16x8*>(nbTc + byte);
                acc = __builtin_amdgcn_mfma_f32_16x16x32_bf16(afrag[kk], bfrag, acc, 0, 0, 0);
            }
            // recover x = n*(s+eps)+u from nbT, multiply, store
            const float uu = u_s[pp];
            const float se = se_s[pp];
            int nbyte = (rowoff + od * 2) ^ swz;
            uint2 nn = *reinterpret_cast<const uint2*>(nbTc + nbyte);
            float x0 = fmaf(bf2f((unsigned short)(nn.x & 0xffffu)), se, uu);
            float x1 = fmaf(bf2f((unsigned short)(nn.x >> 16)),     se, uu);
            float x2 = fmaf(bf2f((unsigned short)(nn.y & 0xffffu)), se, uu);
            float x3 = fmaf(bf2f((unsigned short)(nn.y >> 16)),     se, uu);
            outp[(od + 0) * HW + pp] = x0 * acc[0];
            outp[(od + 1) * HW + pp] = x1 * acc[1];
            outp[(od + 2) * HW + pp] = x2 * acc[2];
            outp[(od + 3) * HW + pp] = x3 * acc[3];
        }
    }
}

extern "C" void kernel_launch(void* const* d_in, const int* in_sizes, int n_in,
                              void* d_out, int out_size, void* d_ws, size_t ws_size,
                              hipStream_t stream) {
    const float* x = (const float*)d_in[0];
    const float* W = (const float*)d_in[1];
    const float* b = (const float*)d_in[2];
    float* out     = (float*)d_out;

    const int nblk = 8 * HW / TILE;            // 4096 blocks
    spnorm_kernel<<<nblk, NT, 0, stream>>>(x, W, b, out);
}